// Round 8
// baseline (250.340 us; speedup 1.0000x reference)
//
#include <hip/hip_runtime.h>
#include <math.h>

#define NBINS 1001
#define KQ 127
#define HALFB 500
#define SEPS 1e-4f
#define NCAND 438   // i = 63 .. 500
#define IMIN 63
#define PMAXN 2048

// ---------- ws layout (uint words) ----------
// ws_u[0]             : absmax bits (float as uint)
// ws_u[2..4)          : packed argmin key (unsigned long long)
// ws_u[4..1005)       : histogram counts (uint, 1001)
// ws_u[1008]          : done counter (uint)
// ws_u[1536..3540)    : csumD[1002] (double, exclusive prefix of f32(hist))
// ws_u[3544..4546)    : nzc[1002]  (int, exclusive prefix of hist!=0)
// ws_u[4608..6656)    : pmax[2048] (float, per-block partial maxes)

static __device__ __forceinline__ float edge_at(int j, float stepv, float negabs) {
    // linspace semantics: edges[j] = j*step + (-absmax), separate rn mul/add (no fma)
    return __fadd_rn(__fmul_rn((float)j, stepv), negabs);
}

// ---------------- block reduction helpers (blockDim.x == 256 = 4 waves) ----------------
static __device__ __forceinline__ void blockSum2(double& a, double& b, double* s8) {
    for (int s = 32; s > 0; s >>= 1) {
        a += __shfl_down(a, s, 64);
        b += __shfl_down(b, s, 64);
    }
    const int w = threadIdx.x >> 6, l = threadIdx.x & 63;
    __syncthreads();
    if (l == 0) { s8[w] = a; s8[4 + w] = b; }
    __syncthreads();
    a = (s8[0] + s8[1]) + (s8[2] + s8[3]);
    b = (s8[4] + s8[5]) + (s8[6] + s8[7]);
}

static __device__ __forceinline__ double blockSum1(double a, double* s8) {
    for (int s = 32; s > 0; s >>= 1) a += __shfl_down(a, s, 64);
    const int w = threadIdx.x >> 6, l = threadIdx.x & 63;
    __syncthreads();
    if (l == 0) s8[w] = a;
    __syncthreads();
    return (s8[0] + s8[1]) + (s8[2] + s8[3]);
}

static __device__ __forceinline__ void blockMax2(float& a, float& b, double* s8) {
    for (int s = 32; s > 0; s >>= 1) {
        a = fmaxf(a, __shfl_down(a, s, 64));
        b = fmaxf(b, __shfl_down(b, s, 64));
    }
    const int w = threadIdx.x >> 6, l = threadIdx.x & 63;
    __syncthreads();
    if (l == 0) { s8[w] = (double)a; s8[4 + w] = (double)b; }
    __syncthreads();
    a = fmaxf(fmaxf((float)s8[0], (float)s8[1]), fmaxf((float)s8[2], (float)s8[3]));
    b = fmaxf(fmaxf((float)s8[4], (float)s8[5]), fmaxf((float)s8[6], (float)s8[7]));
}

// ---------------- kernels ----------------

// per-block partial max -> pmax[blockIdx]; block 0 also zeros hist/absmax/done/packed
__global__ __launch_bounds__(256) void absmax_kernel(const float* __restrict__ x,
                                                     long long n,
                                                     float* __restrict__ pmax,
                                                     unsigned int* __restrict__ ws_u) {
    __shared__ float red[256];
    if (blockIdx.x == 0) {
        for (int t = threadIdx.x; t < NBINS; t += 256) ws_u[4 + t] = 0u;
        if (threadIdx.x == 0) {
            ws_u[0] = 0u;
            ws_u[1008] = 0u;                                  // done counter
            *(unsigned long long*)(ws_u + 2) = ~0ULL;         // packed argmin key
        }
    }
    float m0 = 0.f, m1 = 0.f, m2 = 0.f, m3 = 0.f;
    long long idx = (long long)blockIdx.x * blockDim.x + threadIdx.x;
    long long stride = (long long)gridDim.x * blockDim.x;
    const float4* x4 = (const float4*)x;
    long long n4 = n >> 2;
    long long i = idx;
    for (; i + 3 * stride < n4; i += 4 * stride) {
        float4 a = x4[i];
        float4 b = x4[i + stride];
        float4 c = x4[i + 2 * stride];
        float4 d = x4[i + 3 * stride];
        m0 = fmaxf(m0, fmaxf(fmaxf(fabsf(a.x), fabsf(a.y)), fmaxf(fabsf(a.z), fabsf(a.w))));
        m1 = fmaxf(m1, fmaxf(fmaxf(fabsf(b.x), fabsf(b.y)), fmaxf(fabsf(b.z), fabsf(b.w))));
        m2 = fmaxf(m2, fmaxf(fmaxf(fabsf(c.x), fabsf(c.y)), fmaxf(fabsf(c.z), fabsf(c.w))));
        m3 = fmaxf(m3, fmaxf(fmaxf(fabsf(d.x), fabsf(d.y)), fmaxf(fabsf(d.z), fabsf(d.w))));
    }
    for (; i < n4; i += stride) {
        float4 a = x4[i];
        m0 = fmaxf(m0, fmaxf(fmaxf(fabsf(a.x), fabsf(a.y)), fmaxf(fabsf(a.z), fabsf(a.w))));
    }
    for (long long j = (n4 << 2) + idx; j < n; j += stride)
        m0 = fmaxf(m0, fabsf(x[j]));
    float m = fmaxf(fmaxf(m0, m1), fmaxf(m2, m3));
    red[threadIdx.x] = m;
    __syncthreads();
    for (int s = 128; s > 0; s >>= 1) {
        if (threadIdx.x < s) red[threadIdx.x] = fmaxf(red[threadIdx.x], red[threadIdx.x + s]);
        __syncthreads();
    }
    if (threadIdx.x == 0) pmax[blockIdx.x] = red[0];
}

static __device__ __forceinline__ void bin_one(float v, float inv, float cofs,
                                               float stepv, float negabs,
                                               unsigned int* __restrict__ sh) {
    // fast fma guess; straight-line +/-1 correction restores exact searchsorted
    // semantics (guess provably within 1 of exact bin)
    float t = __builtin_fmaf(v, inv, cofs);
    int b = (int)t;
    b = b < 0 ? 0 : (b > NBINS - 1 ? NBINS - 1 : b);
    float e_lo = edge_at(b, stepv, negabs);
    float e_hi = edge_at(b + 1, stepv, negabs);
    int up = (v >= e_hi) & (b < NBINS - 1);
    int dn = (v < e_lo) & (b > 0);
    b += up - dn;
    // native LDS atomic; no memory clobber so loads can be hoisted across
    unsigned int addr = (unsigned int)(unsigned long long)(&sh[b]);
    asm volatile("ds_add_u32 %0, %1" :: "v"(addr), "v"(1u));
}

__global__ __launch_bounds__(256) void hist_kernel(const float* __restrict__ x,
                                                   long long n,
                                                   const float* __restrict__ pmax,
                                                   unsigned int* __restrict__ hist,
                                                   unsigned int* __restrict__ absmax_bits) {
    __shared__ unsigned int sh[4 * NBINS];   // per-wave private histograms (16 KB)
    __shared__ float redm[256];
    // reduce the partial maxes (L2-hot)
    {
        float m = 0.f;
        for (int t = threadIdx.x; t < PMAXN; t += 256) m = fmaxf(m, pmax[t]);
        redm[threadIdx.x] = m;
        __syncthreads();
        for (int s = 128; s > 0; s >>= 1) {
            if (threadIdx.x < s) redm[threadIdx.x] = fmaxf(redm[threadIdx.x], redm[threadIdx.x + s]);
            __syncthreads();
        }
    }
    float absmax = redm[0];
    if (blockIdx.x == 0 && threadIdx.x == 0) *absmax_bits = __float_as_uint(absmax);

    for (int i = threadIdx.x; i < 4 * NBINS; i += blockDim.x) sh[i] = 0u;
    __syncthreads();
    unsigned int* mysh = sh + (threadIdx.x >> 6) * NBINS;

    float negabs = -absmax;
    float stepv = __fdiv_rn(__fmul_rn(2.0f, absmax), 1001.0f);
    float inv = __fdiv_rn(1001.0f, __fmul_rn(2.0f, absmax));
    float cofs = __fmul_rn(absmax, inv);

    long long idx = (long long)blockIdx.x * blockDim.x + threadIdx.x;
    long long stride = (long long)gridDim.x * blockDim.x;
    const float4* x4 = (const float4*)x;
    long long n4 = n >> 2;
    long long i = idx;
    for (; i + 3 * stride < n4; i += 4 * stride) {
        float4 a = x4[i];
        float4 b = x4[i + stride];
        float4 c = x4[i + 2 * stride];
        float4 d = x4[i + 3 * stride];
        bin_one(a.x, inv, cofs, stepv, negabs, mysh);
        bin_one(a.y, inv, cofs, stepv, negabs, mysh);
        bin_one(a.z, inv, cofs, stepv, negabs, mysh);
        bin_one(a.w, inv, cofs, stepv, negabs, mysh);
        bin_one(b.x, inv, cofs, stepv, negabs, mysh);
        bin_one(b.y, inv, cofs, stepv, negabs, mysh);
        bin_one(b.z, inv, cofs, stepv, negabs, mysh);
        bin_one(b.w, inv, cofs, stepv, negabs, mysh);
        bin_one(c.x, inv, cofs, stepv, negabs, mysh);
        bin_one(c.y, inv, cofs, stepv, negabs, mysh);
        bin_one(c.z, inv, cofs, stepv, negabs, mysh);
        bin_one(c.w, inv, cofs, stepv, negabs, mysh);
        bin_one(d.x, inv, cofs, stepv, negabs, mysh);
        bin_one(d.y, inv, cofs, stepv, negabs, mysh);
        bin_one(d.z, inv, cofs, stepv, negabs, mysh);
        bin_one(d.w, inv, cofs, stepv, negabs, mysh);
    }
    for (; i < n4; i += stride) {
        float4 a = x4[i];
        bin_one(a.x, inv, cofs, stepv, negabs, mysh);
        bin_one(a.y, inv, cofs, stepv, negabs, mysh);
        bin_one(a.z, inv, cofs, stepv, negabs, mysh);
        bin_one(a.w, inv, cofs, stepv, negabs, mysh);
    }
    for (long long j = (n4 << 2) + idx; j < n; j += stride)
        bin_one(x[j], inv, cofs, stepv, negabs, mysh);

    // drain our asm ds_adds and tell the compiler LDS changed before re-reading
    asm volatile("s_waitcnt lgkmcnt(0)" ::: "memory");
    __syncthreads();
    for (int i2 = threadIdx.x; i2 < NBINS; i2 += blockDim.x) {
        unsigned int s = sh[i2] + sh[NBINS + i2] + sh[2 * NBINS + i2] + sh[3 * NBINS + i2];
        if (s) atomicAdd(&hist[i2], s);
    }
}

// exclusive prefix sums over f32-rounded counts (double) and nonzero flags (int)
__global__ __launch_bounds__(1024) void scan_kernel(const unsigned int* __restrict__ hist,
                                                    double* __restrict__ csumD,
                                                    int* __restrict__ nzc) {
    __shared__ double sd[1024];
    __shared__ int si[1024];
    int t = threadIdx.x;
    unsigned int h = (t < NBINS) ? hist[t] : 0u;
    sd[t] = (double)((float)h);          // f32-round counts like reference astype(float32)
    si[t] = (t < NBINS && h != 0u) ? 1 : 0;
    __syncthreads();
    for (int off = 1; off < 1024; off <<= 1) {
        double dv = 0.0; int iv = 0;
        if (t >= off) { dv = sd[t - off]; iv = si[t - off]; }
        __syncthreads();
        sd[t] += dv; si[t] += iv;
        __syncthreads();
    }
    if (t < NBINS) { csumD[t + 1] = sd[t]; nzc[t + 1] = si[t]; }
    if (t == 0) { csumD[0] = 0.0; nzc[0] = 0; }
}

__global__ __launch_bounds__(256) void cand_kernel(const unsigned int* __restrict__ hist,
                                                   const double* __restrict__ csumD,
                                                   const int* __restrict__ nzc,
                                                   unsigned int* __restrict__ ws_u,
                                                   float* __restrict__ out) {
    const int i = IMIN + (int)blockIdx.x;   // 63..500
    const int L = 2 * i + 1;                // 127..1001
    const int start = HALFB - i;
    const int stop = start + L;
    const int m = L / KQ;                   // 1..7
    const unsigned int magic = (65536u + (unsigned)m - 1u) / (unsigned)m;  // k/m = (k*magic)>>16, k<=1000
    const int tid = threadIdx.x;

    __shared__ float s_h[NBINS];
    __shared__ float s_qb[KQ];
    __shared__ float s_nkf[KQ];
    __shared__ double s8[8];

    for (int k = tid; k < NBINS; k += 256) s_h[k] = (float)hist[k];

    // ---- scalar prework ----
    double csS = csumD[start], csE = csumD[stop], total = csumD[NBINS];
    float left = (float)csS;
    float right = (float)(total - csE);
    float s0 = (float)hist[start];
    float sL1 = (float)hist[stop - 1];
    int nzwin = nzc[stop] - nzc[start];
    int nnzq = nzwin - ((sL1 != 0.f) ? 1 : 0);
    int nzeros_s = L - nzwin;
    float n_zeros_p = (float)(nzeros_s
                              - ((s0 == 0.f && csS > 0.0) ? 1 : 0)
                              - ((sL1 == 0.f && (total - csE) > 0.0) ? 1 : 0));

    float n_nz_p = (float)L - n_zeros_p;
    float eps1p = SEPS * n_zeros_p / fmaxf(n_nz_p, 1.0f);
    float cp = eps1p * n_nz_p;

    float n_zeros_q = (float)L - (float)nnzq;
    float n_nz_qf = (float)L - n_zeros_q;
    float eps1q = SEPS * n_zeros_q / fmaxf(n_nz_qf, 1.0f);
    float cq = eps1q * n_nz_qf;

    // ---- segment sums from prefix arrays ----
    if (tid < KQ) {
        int lo = start + tid * m;
        int hi = (tid == KQ - 1) ? stop : (lo + m);
        s_qb[tid] = (float)(csumD[hi] - csumD[lo]);
        int nrm = (nzc[hi] - nzc[lo]) - ((tid == KQ - 1 && sL1 != 0.f) ? 1 : 0);
        s_nkf[tid] = (float)nrm;
    }
    __syncthreads();

    // ---- pass 1: logit precursors + maxes ----
    float ppre[4], qpre[4];
    float maxpp = -INFINITY, maxqq = -INFINITY;
#pragma unroll
    for (int j = 0; j < 4; ++j) {
        int k = tid + 256 * j;
        ppre[j] = 0.f; qpre[j] = 0.f;
        if (k < L) {
            float s = s_h[start + k];
            float p = s;
            if (k == 0) p += left;
            if (k == L - 1) p += right;
            float pp = (p == 0.f) ? SEPS : p;
            int seg = (int)(((unsigned)k * magic) >> 16);
            if (seg > KQ - 1) seg = KQ - 1;
            float qv = 0.f;
            if (s != 0.f && k != L - 1) {
                float nk = s_nkf[seg];
                if (nk > 0.f) qv = s_qb[seg] / nk;
            }
            float qq = (qv == 0.f) ? SEPS : qv;
            ppre[j] = pp; qpre[j] = qq;
            maxpp = fmaxf(maxpp, pp);
            maxqq = fmaxf(maxqq, qq);
        }
    }
    blockMax2(maxpp, maxqq, s8);
    float maxplog = maxpp - cp;
    float maxqlog = maxqq - cq;

    // ---- pass 2: logsumexp sums ----
    double sp = 0.0, sq = 0.0;
#pragma unroll
    for (int j = 0; j < 4; ++j) {
        int k = tid + 256 * j;
        if (k < L) {
            sp += (double)expf((ppre[j] - cp) - maxplog);
            sq += (double)expf((qpre[j] - cq) - maxqlog);
        }
    }
    blockSum2(sp, sq, s8);
    float lZp = maxplog + (float)log(sp);
    float lZq = maxqlog + (float)log(sq);

    // ---- pass 3: KL ----
    double kll = 0.0;
#pragma unroll
    for (int j = 0; j < 4; ++j) {
        int k = tid + 256 * j;
        if (k < L) {
            float pl = ppre[j] - cp;
            float ql = qpre[j] - cq;
            float lp = pl - lZp;
            float lq = ql - lZq;
            kll += (double)(expf(lp) * (lp - lq));
        }
    }
    double KL = blockSum1(kll, s8);

    // ---- fused argmin epilogue (replaces argmin_kernel) ----
    if (tid == 0) {
        float kl = (nnzq > 0) ? (float)KL : INFINITY;
        // order-preserving map float -> uint (handles negatives and inf)
        unsigned int u = __float_as_uint(kl);
        u = (u & 0x80000000u) ? ~u : (u | 0x80000000u);
        unsigned long long key = ((unsigned long long)u << 16) | (unsigned int)blockIdx.x;
        unsigned long long* packed = (unsigned long long*)(ws_u + 2);
        atomicMin(packed, key);
        __threadfence();
        unsigned int prev = atomicAdd(&ws_u[1008], 1u);
        if (prev == NCAND - 1) {
            // last block: winner is final
            unsigned long long win = atomicAdd(packed, 0ULL);   // device-scope read
            int widx = (int)(win & 0xFFFFull);
            int wi = IMIN + widx;
            int wstop = HALFB + wi + 1;
            float absmax = __uint_as_float(ws_u[0]);
            float stepv = __fdiv_rn(__fmul_rn(2.0f, absmax), 1001.0f);
            out[0] = __fadd_rn(__fmul_rn((float)wstop, stepv), -absmax);
        }
    }
}

extern "C" void kernel_launch(void* const* d_in, const int* in_sizes, int n_in,
                              void* d_out, int out_size, void* d_ws, size_t ws_size,
                              hipStream_t stream) {
    const float* x = (const float*)d_in[0];
    long long n = (long long)in_sizes[0];

    unsigned int* ws_u = (unsigned int*)d_ws;
    unsigned int* absmax_bits = ws_u;                 // word 0
    unsigned int* hist = ws_u + 4;                    // words 4 .. 1005
    double* csumD = (double*)(ws_u + 1536);           // words 1536 .. 3540
    int* nzc = (int*)(ws_u + 3544);                   // words 3544 .. 4546
    float* pmax = (float*)(ws_u + 4608);              // words 4608 .. 6656
    float* out = (float*)d_out;

    hipLaunchKernelGGL(absmax_kernel, dim3(PMAXN), dim3(256), 0, stream, x, n, pmax, ws_u);
    hipLaunchKernelGGL(hist_kernel, dim3(1024), dim3(256), 0, stream, x, n, pmax, hist, absmax_bits);
    hipLaunchKernelGGL(scan_kernel, dim3(1), dim3(1024), 0, stream, hist, csumD, nzc);
    hipLaunchKernelGGL(cand_kernel, dim3(NCAND), dim3(256), 0, stream, hist, csumD, nzc, ws_u, out);
}

// Round 10
// 238.829 us; speedup vs baseline: 1.0482x; 1.0482x over previous
//
#include <hip/hip_runtime.h>
#include <math.h>

#define NBINS 1001
#define KQ 127
#define HALFB 500
#define SEPS 1e-4f
#define NCAND 438   // i = 63 .. 500
#define IMIN 63
#define PMAXN 2048

typedef float vfloat4 __attribute__((ext_vector_type(4)));

// non-temporal 16B load: nt flag -> bypass/minimize cache residency
static __device__ __forceinline__ vfloat4 ntload4(const vfloat4* p) {
    return __builtin_nontemporal_load(p);
}

// ---------- ws layout (uint words) ----------
// ws_u[0]             : absmax bits (float as uint)
// ws_u[4..1005)       : histogram counts (uint, 1001)
// ws_u[1028..1466)    : divergence[438] (float)
// ws_u[1536..3540)    : csumD[1002] (double, exclusive prefix of f32(hist))
// ws_u[3544..4546)    : nzc[1002]  (int, exclusive prefix of hist!=0)
// ws_u[4608..6656)    : pmax[2048] (float, per-block partial maxes)

static __device__ __forceinline__ float edge_at(int j, float stepv, float negabs) {
    // linspace semantics: edges[j] = j*step + (-absmax), separate rn mul/add (no fma)
    return __fadd_rn(__fmul_rn((float)j, stepv), negabs);
}

// ---------------- block reduction helpers (blockDim.x == 256 = 4 waves) ----------------
static __device__ __forceinline__ void blockSum2(double& a, double& b, double* s8) {
    for (int s = 32; s > 0; s >>= 1) {
        a += __shfl_down(a, s, 64);
        b += __shfl_down(b, s, 64);
    }
    const int w = threadIdx.x >> 6, l = threadIdx.x & 63;
    __syncthreads();
    if (l == 0) { s8[w] = a; s8[4 + w] = b; }
    __syncthreads();
    a = (s8[0] + s8[1]) + (s8[2] + s8[3]);
    b = (s8[4] + s8[5]) + (s8[6] + s8[7]);
}

static __device__ __forceinline__ double blockSum1(double a, double* s8) {
    for (int s = 32; s > 0; s >>= 1) a += __shfl_down(a, s, 64);
    const int w = threadIdx.x >> 6, l = threadIdx.x & 63;
    __syncthreads();
    if (l == 0) s8[w] = a;
    __syncthreads();
    return (s8[0] + s8[1]) + (s8[2] + s8[3]);
}

static __device__ __forceinline__ void blockMax2(float& a, float& b, double* s8) {
    for (int s = 32; s > 0; s >>= 1) {
        a = fmaxf(a, __shfl_down(a, s, 64));
        b = fmaxf(b, __shfl_down(b, s, 64));
    }
    const int w = threadIdx.x >> 6, l = threadIdx.x & 63;
    __syncthreads();
    if (l == 0) { s8[w] = (double)a; s8[4 + w] = (double)b; }
    __syncthreads();
    a = fmaxf(fmaxf((float)s8[0], (float)s8[1]), fmaxf((float)s8[2], (float)s8[3]));
    b = fmaxf(fmaxf((float)s8[4], (float)s8[5]), fmaxf((float)s8[6], (float)s8[7]));
}

// ---------------- kernels ----------------

// per-block partial max -> pmax[blockIdx]; block 0 also zeros hist + absmax word
__global__ __launch_bounds__(256) void absmax_kernel(const float* __restrict__ x,
                                                     long long n,
                                                     float* __restrict__ pmax,
                                                     unsigned int* __restrict__ ws_u) {
    __shared__ float red[256];
    if (blockIdx.x == 0) {
        for (int t = threadIdx.x; t < NBINS; t += 256) ws_u[4 + t] = 0u;
        if (threadIdx.x == 0) ws_u[0] = 0u;
    }
    float m = 0.f;
    long long idx = (long long)blockIdx.x * blockDim.x + threadIdx.x;
    long long stride = (long long)gridDim.x * blockDim.x;
    const vfloat4* x4 = (const vfloat4*)x;
    long long n4 = n >> 2;
    long long i = idx;
    for (; i + stride < n4; i += 2 * stride) {
        vfloat4 a = ntload4(&x4[i]);
        vfloat4 b = ntload4(&x4[i + stride]);
        m = fmaxf(m, fmaxf(fmaxf(fabsf(a.x), fabsf(a.y)), fmaxf(fabsf(a.z), fabsf(a.w))));
        m = fmaxf(m, fmaxf(fmaxf(fabsf(b.x), fabsf(b.y)), fmaxf(fabsf(b.z), fabsf(b.w))));
    }
    for (; i < n4; i += stride) {
        vfloat4 a = ntload4(&x4[i]);
        m = fmaxf(m, fmaxf(fmaxf(fabsf(a.x), fabsf(a.y)), fmaxf(fabsf(a.z), fabsf(a.w))));
    }
    for (long long j = (n4 << 2) + idx; j < n; j += stride)
        m = fmaxf(m, fabsf(x[j]));
    red[threadIdx.x] = m;
    __syncthreads();
    for (int s = 128; s > 0; s >>= 1) {
        if (threadIdx.x < s) red[threadIdx.x] = fmaxf(red[threadIdx.x], red[threadIdx.x + s]);
        __syncthreads();
    }
    if (threadIdx.x == 0) pmax[blockIdx.x] = red[0];
}

static __device__ __forceinline__ void bin_one(float v, float inv, float cofs,
                                               float stepv, float negabs,
                                               unsigned int* __restrict__ sh) {
    // fast fma guess; straight-line +/-1 correction restores exact searchsorted
    // semantics (guess provably within 1 of exact bin)
    float t = __builtin_fmaf(v, inv, cofs);
    int b = (int)t;
    b = b < 0 ? 0 : (b > NBINS - 1 ? NBINS - 1 : b);
    float e_lo = edge_at(b, stepv, negabs);
    float e_hi = edge_at(b + 1, stepv, negabs);
    int up = (v >= e_hi) & (b < NBINS - 1);
    int dn = (v < e_lo) & (b > 0);
    b += up - dn;
    // native LDS atomic; no memory clobber so loads can be hoisted across
    unsigned int addr = (unsigned int)(unsigned long long)(&sh[b]);
    asm volatile("ds_add_u32 %0, %1" :: "v"(addr), "v"(1u));
}

__global__ __launch_bounds__(256) void hist_kernel(const float* __restrict__ x,
                                                   long long n,
                                                   const float* __restrict__ pmax,
                                                   unsigned int* __restrict__ hist,
                                                   unsigned int* __restrict__ absmax_bits) {
    __shared__ unsigned int sh[4 * NBINS];   // per-wave private histograms (16 KB)
    __shared__ float redm[256];
    // reduce the partial maxes (L2-hot)
    {
        float m = 0.f;
        for (int t = threadIdx.x; t < PMAXN; t += 256) m = fmaxf(m, pmax[t]);
        redm[threadIdx.x] = m;
        __syncthreads();
        for (int s = 128; s > 0; s >>= 1) {
            if (threadIdx.x < s) redm[threadIdx.x] = fmaxf(redm[threadIdx.x], redm[threadIdx.x + s]);
            __syncthreads();
        }
    }
    float absmax = redm[0];
    if (blockIdx.x == 0 && threadIdx.x == 0) *absmax_bits = __float_as_uint(absmax);

    for (int i = threadIdx.x; i < 4 * NBINS; i += blockDim.x) sh[i] = 0u;
    __syncthreads();
    unsigned int* mysh = sh + (threadIdx.x >> 6) * NBINS;

    float negabs = -absmax;
    float stepv = __fdiv_rn(__fmul_rn(2.0f, absmax), 1001.0f);
    float inv = __fdiv_rn(1001.0f, __fmul_rn(2.0f, absmax));
    float cofs = __fmul_rn(absmax, inv);

    long long idx = (long long)blockIdx.x * blockDim.x + threadIdx.x;
    long long stride = (long long)gridDim.x * blockDim.x;
    const vfloat4* x4 = (const vfloat4*)x;
    long long n4 = n >> 2;
    long long i = idx;
    for (; i + stride < n4; i += 2 * stride) {
        vfloat4 a = ntload4(&x4[i]);
        vfloat4 b = ntload4(&x4[i + stride]);
        bin_one(a.x, inv, cofs, stepv, negabs, mysh);
        bin_one(a.y, inv, cofs, stepv, negabs, mysh);
        bin_one(a.z, inv, cofs, stepv, negabs, mysh);
        bin_one(a.w, inv, cofs, stepv, negabs, mysh);
        bin_one(b.x, inv, cofs, stepv, negabs, mysh);
        bin_one(b.y, inv, cofs, stepv, negabs, mysh);
        bin_one(b.z, inv, cofs, stepv, negabs, mysh);
        bin_one(b.w, inv, cofs, stepv, negabs, mysh);
    }
    for (; i < n4; i += stride) {
        vfloat4 a = ntload4(&x4[i]);
        bin_one(a.x, inv, cofs, stepv, negabs, mysh);
        bin_one(a.y, inv, cofs, stepv, negabs, mysh);
        bin_one(a.z, inv, cofs, stepv, negabs, mysh);
        bin_one(a.w, inv, cofs, stepv, negabs, mysh);
    }
    for (long long j = (n4 << 2) + idx; j < n; j += stride)
        bin_one(x[j], inv, cofs, stepv, negabs, mysh);

    // drain our asm ds_adds and tell the compiler LDS changed before re-reading
    asm volatile("s_waitcnt lgkmcnt(0)" ::: "memory");
    __syncthreads();
    for (int i2 = threadIdx.x; i2 < NBINS; i2 += blockDim.x) {
        unsigned int s = sh[i2] + sh[NBINS + i2] + sh[2 * NBINS + i2] + sh[3 * NBINS + i2];
        if (s) atomicAdd(&hist[i2], s);
    }
}

// exclusive prefix sums over f32-rounded counts (double) and nonzero flags (int)
__global__ __launch_bounds__(1024) void scan_kernel(const unsigned int* __restrict__ hist,
                                                    double* __restrict__ csumD,
                                                    int* __restrict__ nzc) {
    __shared__ double sd[1024];
    __shared__ int si[1024];
    int t = threadIdx.x;
    unsigned int h = (t < NBINS) ? hist[t] : 0u;
    sd[t] = (double)((float)h);          // f32-round counts like reference astype(float32)
    si[t] = (t < NBINS && h != 0u) ? 1 : 0;
    __syncthreads();
    for (int off = 1; off < 1024; off <<= 1) {
        double dv = 0.0; int iv = 0;
        if (t >= off) { dv = sd[t - off]; iv = si[t - off]; }
        __syncthreads();
        sd[t] += dv; si[t] += iv;
        __syncthreads();
    }
    if (t < NBINS) { csumD[t + 1] = sd[t]; nzc[t + 1] = si[t]; }
    if (t == 0) { csumD[0] = 0.0; nzc[0] = 0; }
}

__global__ __launch_bounds__(256) void cand_kernel(const unsigned int* __restrict__ hist,
                                                   const double* __restrict__ csumD,
                                                   const int* __restrict__ nzc,
                                                   float* __restrict__ divg) {
    const int i = IMIN + (int)blockIdx.x;   // 63..500
    const int L = 2 * i + 1;                // 127..1001
    const int start = HALFB - i;
    const int stop = start + L;
    const int m = L / KQ;                   // 1..7
    const unsigned int magic = (65536u + (unsigned)m - 1u) / (unsigned)m;  // k/m = (k*magic)>>16, k<=1000
    const int tid = threadIdx.x;

    __shared__ float s_h[NBINS];
    __shared__ float s_qb[KQ];
    __shared__ float s_nkf[KQ];
    __shared__ double s8[8];

    for (int k = tid; k < NBINS; k += 256) s_h[k] = (float)hist[k];

    // ---- scalar prework (no reductions needed) ----
    double csS = csumD[start], csE = csumD[stop], total = csumD[NBINS];
    float left = (float)csS;
    float right = (float)(total - csE);
    float s0 = (float)hist[start];
    float sL1 = (float)hist[stop - 1];
    int nzwin = nzc[stop] - nzc[start];         // # nonzero sliced in window
    int nnzq = nzwin - ((sL1 != 0.f) ? 1 : 0);  // q nonzero <=> s!=0 && k!=L-1
    int nzeros_s = L - nzwin;
    // p==0 iff s==0 and (k!=0 or left==0) and (k!=L-1 or right==0)
    float n_zeros_p = (float)(nzeros_s
                              - ((s0 == 0.f && csS > 0.0) ? 1 : 0)
                              - ((sL1 == 0.f && (total - csE) > 0.0) ? 1 : 0));

    float n_nz_p = (float)L - n_zeros_p;
    float eps1p = SEPS * n_zeros_p / fmaxf(n_nz_p, 1.0f);
    float cp = eps1p * n_nz_p;

    float n_zeros_q = (float)L - (float)nnzq;
    float n_nz_qf = (float)L - n_zeros_q;
    float eps1q = SEPS * n_zeros_q / fmaxf(n_nz_qf, 1.0f);
    float cq = eps1q * n_nz_qf;

    // ---- segment sums from prefix arrays (no atomics) ----
    if (tid < KQ) {
        int lo = start + tid * m;
        int hi = (tid == KQ - 1) ? stop : (lo + m);
        s_qb[tid] = (float)(csumD[hi] - csumD[lo]);
        int nrm = (nzc[hi] - nzc[lo]) - ((tid == KQ - 1 && sL1 != 0.f) ? 1 : 0);
        s_nkf[tid] = (float)nrm;
    }
    __syncthreads();   // covers s_h, s_qb, s_nkf

    // ---- pass 1: logit precursors + maxes ----
    float ppre[4], qpre[4];
    float maxpp = -INFINITY, maxqq = -INFINITY;
#pragma unroll
    for (int j = 0; j < 4; ++j) {
        int k = tid + 256 * j;
        ppre[j] = 0.f; qpre[j] = 0.f;
        if (k < L) {
            float s = s_h[start + k];
            float p = s;
            if (k == 0) p += left;
            if (k == L - 1) p += right;
            float pp = (p == 0.f) ? SEPS : p;
            int seg = (int)(((unsigned)k * magic) >> 16);
            if (seg > KQ - 1) seg = KQ - 1;   // remainder bins -> last merged bin
            float qv = 0.f;
            if (s != 0.f && k != L - 1) {
                float nk = s_nkf[seg];
                if (nk > 0.f) qv = s_qb[seg] / nk;
            }
            float qq = (qv == 0.f) ? SEPS : qv;
            ppre[j] = pp; qpre[j] = qq;
            maxpp = fmaxf(maxpp, pp);
            maxqq = fmaxf(maxqq, qq);
        }
    }
    blockMax2(maxpp, maxqq, s8);
    float maxplog = maxpp - cp;
    float maxqlog = maxqq - cq;

    // ---- pass 2: logsumexp sums ----
    double sp = 0.0, sq = 0.0;
#pragma unroll
    for (int j = 0; j < 4; ++j) {
        int k = tid + 256 * j;
        if (k < L) {
            sp += (double)expf((ppre[j] - cp) - maxplog);
            sq += (double)expf((qpre[j] - cq) - maxqlog);
        }
    }
    blockSum2(sp, sq, s8);
    float lZp = maxplog + (float)log(sp);
    float lZq = maxqlog + (float)log(sq);

    // ---- pass 3: KL ----
    double kll = 0.0;
#pragma unroll
    for (int j = 0; j < 4; ++j) {
        int k = tid + 256 * j;
        if (k < L) {
            float pl = ppre[j] - cp;
            float ql = qpre[j] - cq;
            float lp = pl - lZp;
            float lq = ql - lZq;
            kll += (double)(expf(lp) * (lp - lq));
        }
    }
    double KL = blockSum1(kll, s8);
    if (tid == 0) divg[blockIdx.x] = (nnzq > 0) ? (float)KL : INFINITY;
}

__global__ void argmin_kernel(const float* __restrict__ divg,
                              const unsigned int* __restrict__ absmax_bits,
                              float* __restrict__ out) {
    __shared__ float vals[512];
    __shared__ int idxs[512];
    int tid = threadIdx.x;
    vals[tid] = (tid < NCAND) ? divg[tid] : INFINITY;
    idxs[tid] = tid;
    __syncthreads();
    for (int s = 256; s > 0; s >>= 1) {
        if (tid < s) {
            float a = vals[tid], b = vals[tid + s];
            int ia = idxs[tid], ib = idxs[tid + s];
            if (b < a || (b == a && ib < ia)) { vals[tid] = b; idxs[tid] = ib; }
        }
        __syncthreads();
    }
    if (tid == 0) {
        int i = IMIN + idxs[0];
        int stop = HALFB + i + 1;
        float absmax = __uint_as_float(*absmax_bits);
        float stepv = __fdiv_rn(__fmul_rn(2.0f, absmax), 1001.0f);
        out[0] = __fadd_rn(__fmul_rn((float)stop, stepv), -absmax);
    }
}

extern "C" void kernel_launch(void* const* d_in, const int* in_sizes, int n_in,
                              void* d_out, int out_size, void* d_ws, size_t ws_size,
                              hipStream_t stream) {
    const float* x = (const float*)d_in[0];
    long long n = (long long)in_sizes[0];

    unsigned int* ws_u = (unsigned int*)d_ws;
    unsigned int* absmax_bits = ws_u;                 // word 0
    unsigned int* hist = ws_u + 4;                    // words 4 .. 1005
    float* divg = (float*)(ws_u + 1028);              // words 1028 .. 1466
    double* csumD = (double*)(ws_u + 1536);           // words 1536 .. 3540
    int* nzc = (int*)(ws_u + 3544);                   // words 3544 .. 4546
    float* pmax = (float*)(ws_u + 4608);              // words 4608 .. 6656
    float* out = (float*)d_out;

    hipLaunchKernelGGL(absmax_kernel, dim3(PMAXN), dim3(256), 0, stream, x, n, pmax, ws_u);
    hipLaunchKernelGGL(hist_kernel, dim3(1024), dim3(256), 0, stream, x, n, pmax, hist, absmax_bits);
    hipLaunchKernelGGL(scan_kernel, dim3(1), dim3(1024), 0, stream, hist, csumD, nzc);
    hipLaunchKernelGGL(cand_kernel, dim3(NCAND), dim3(256), 0, stream, hist, csumD, nzc, divg);
    hipLaunchKernelGGL(argmin_kernel, dim3(1), dim3(512), 0, stream, divg, absmax_bits, out);
}